// Round 7
// baseline (57.315 us; speedup 1.0000x reference)
//
#include <hip/hip_runtime.h>

// Problem constants (match reference file)
#define S_LEN 512
#define B_SZ  512
#define D_DIM 256
#define SEP_ID 13
#define PAD_ID 1

#define NTHR   256
#define ROWS_PER_WAVE 32
#define ROWS_PER_BLOCK 128                            // 4 waves x 32 rows, all same s
#define NROWS  (S_LEN * B_SZ)                         // 262144
#define NBLK   (NROWS / ROWS_PER_BLOCK)               // 2048 blocks

typedef float f32x4 __attribute__((ext_vector_type(4)));

// Kernel 1: wave-parallel inner-padding state machine. Output is PACKED
// metadata per row: low 16 = token id (<512), high 16 = pidx+1 (0 = skip).
__global__ void emb_scan_wave(const int* __restrict__ seq,
                              unsigned* __restrict__ pack) {
    const int lane = threadIdx.x & 63;
    const int b = blockIdx.x * (blockDim.x >> 6) + (threadIdx.x >> 6);
    if (b >= B_SZ) return;

    const int s0 = lane * (S_LEN / 64);      // 8 positions per lane
    int toks[8];
#pragma unroll
    for (int k = 0; k < 8; ++k) toks[k] = seq[(s0 + k) * B_SZ + b];

    // Local transfer function over this lane's 8 tokens: f(p) = A | (p & B)
    unsigned A = 0u, Bf = 1u;
#pragma unroll
    for (int k = 0; k < 8; ++k) {
        unsigned a  = (toks[k] == SEP_ID) ? 1u : 0u;
        unsigned bb = (toks[k] == PAD_ID) ? 1u : 0u;
        A  = a | (A & bb);
        Bf = Bf & bb;
    }

    // Inclusive Kogge-Stone scan of function composition (lower lanes first)
    unsigned incA = A, incB = Bf;
    for (int d = 1; d < 64; d <<= 1) {
        unsigned Al = __shfl_up(incA, d, 64);
        unsigned Bl = __shfl_up(incB, d, 64);
        if (lane >= d) {
            incA = incA | (Al & incB);
            incB = Bl & incB;
        }
    }
    unsigned pin = __shfl_up(incA, 1, 64);
    if (lane == 0) pin = 0u;

    // Recompute the 8 steps with the true incoming state
    unsigned p = pin, skipbits = 0u;
    int cnt = 0;
#pragma unroll
    for (int k = 0; k < 8; ++k) {
        unsigned a  = (toks[k] == SEP_ID) ? 1u : 0u;
        unsigned bb = (toks[k] == PAD_ID) ? 1u : 0u;
        unsigned skip = p & bb;
        skipbits |= skip << k;
        cnt += (int)skip;
        p = a | skip;
    }

    // Exclusive prefix sum of per-lane skip counts -> pad_num at lane start
    int pref = cnt;
    for (int d = 1; d < 64; d <<= 1) {
        int v = __shfl_up(pref, d, 64);
        if (lane >= d) pref += v;
    }
    pref -= cnt;

    int pad = pref;
#pragma unroll
    for (int k = 0; k < 8; ++k) {
        int s = s0 + k;
        unsigned skip = (skipbits >> k) & 1u;
        unsigned p1 = skip ? 0u : (unsigned)(s - pad + 1);   // pidx+1, 0=skip
        pack[s * B_SZ + b] = (unsigned)toks[k] | (p1 << 16);
        pad += (int)skip;
    }
}

// Kernel 2: fused gather+add, VMEM-minimized.
// A wave's 32 rows all share one s. pe[s] is hoisted to registers once; a
// scalar pre-check detects the (common, ~94%) case where all 32 rows have
// pidx==s, and runs a 2-VMEM/iteration loop (tw gather + store). The dirty
// path falls back to per-row pe gathers.
__global__ void __launch_bounds__(NTHR)
emb_fused_kernel(const unsigned* __restrict__ pack,
                 const float* __restrict__ tw,
                 const float* __restrict__ pe,
                 float* __restrict__ out) {
    const unsigned lane  = threadIdx.x & 63u;
    const unsigned wid_s = (unsigned)__builtin_amdgcn_readfirstlane(threadIdx.x >> 6);
    const unsigned row0  = blockIdx.x * ROWS_PER_BLOCK + wid_s * ROWS_PER_WAVE;
    const unsigned s_row = row0 >> 9;                 // row0 / B_SZ, uniform
    const unsigned doff  = lane * 4u;

    const unsigned* __restrict__ packp = pack + row0;   // wave-uniform pointer
    float* orow = out + (size_t)row0 * D_DIM + doff;

    // Hoisted positional row pe[s] (the value for every clean row).
    const f32x4 pv_s = *(const f32x4*)(pe + (size_t)s_row * D_DIM + doff);

    // Scalar pre-check: all 32 rows clean (pidx == s)?
    const unsigned want = (s_row + 1u) << 16;
    bool clean = true;
#pragma unroll
    for (int it = 0; it < ROWS_PER_WAVE; ++it)
        clean = clean && ((packp[it] & 0xFFFF0000u) == want);

    if (clean) {
        // Fast path: 2 VMEM instrs per 1KB written.
#pragma unroll 8
        for (int it = 0; it < ROWS_PER_WAVE; ++it) {
            const unsigned tok = packp[it] & 0xFFFFu;
            const f32x4 tv = *(const f32x4*)(tw + (size_t)tok * D_DIM + doff);
            *(f32x4*)(orow + (size_t)it * D_DIM) = tv + pv_s;
        }
    } else {
        // General path: per-row pe gather with skip masking.
#pragma unroll 8
        for (int it = 0; it < ROWS_PER_WAVE; ++it) {
            const unsigned m   = packp[it];
            const unsigned tok = m & 0xFFFFu;
            const int      p1  = (int)(m >> 16);

            const f32x4 tv = *(const f32x4*)(tw + (size_t)tok * D_DIM + doff);
            const int   pc = (p1 <= 0) ? 0 : (p1 - 1);
            const f32x4 pv = *(const f32x4*)(pe + (size_t)pc * D_DIM + doff);
            const float pm = (p1 == 0) ? 0.0f : 1.0f;

            *(f32x4*)(orow + (size_t)it * D_DIM) = tv + pv * pm;
        }
    }
}

extern "C" void kernel_launch(void* const* d_in, const int* in_sizes, int n_in,
                              void* d_out, int out_size, void* d_ws, size_t ws_size,
                              hipStream_t stream) {
    const int*   seq = (const int*)d_in[0];    // [S, B] int32
    const float* tw  = (const float*)d_in[1];  // [VOCAB, D] f32
    const float* pe  = (const float*)d_in[2];  // [MAX_LEN, D] f32
    float* out = (float*)d_out;                // [S, B, D] f32
    unsigned* pack = (unsigned*)d_ws;          // [S, B] packed meta (1 MiB)

    // 1) wave-parallel scan: 512 columns, 1 wave each -> 128 blocks x 256
    emb_scan_wave<<<dim3(B_SZ / 4), dim3(256), 0, stream>>>(seq, pack);

    // 2) fused gather+add: 2048 blocks x 256, 128 contiguous rows per block
    emb_fused_kernel<<<dim3(NBLK), dim3(NTHR), 0, stream>>>(pack, tw, pe, out);
}

// Round 8
// 56.667 us; speedup vs baseline: 1.0114x; 1.0114x over previous
//
#include <hip/hip_runtime.h>

// Problem constants (match reference file)
#define S_LEN 512
#define B_SZ  512
#define D_DIM 256
#define SEP_ID 13
#define PAD_ID 1

#define NTHR   256
#define ROWS_PER_WAVE 32
#define ROWS_PER_BLOCK 128                            // 4 waves x 32 rows, all same s
#define NROWS  (S_LEN * B_SZ)                         // 262144
#define NBLK   (NROWS / ROWS_PER_BLOCK)               // 2048 blocks

typedef float f32x4 __attribute__((ext_vector_type(4)));

// Kernel 1: wave-parallel inner-padding state machine (identical to R6).
__global__ void emb_scan_wave(const int* __restrict__ seq,
                              int* __restrict__ idx) {
    const int lane = threadIdx.x & 63;
    const int b = blockIdx.x * (blockDim.x >> 6) + (threadIdx.x >> 6);
    if (b >= B_SZ) return;

    const int s0 = lane * (S_LEN / 64);      // 8 positions per lane
    int toks[8];
#pragma unroll
    for (int k = 0; k < 8; ++k) toks[k] = seq[(s0 + k) * B_SZ + b];

    // Local transfer function over this lane's 8 tokens: f(p) = A | (p & B)
    unsigned A = 0u, Bf = 1u;
#pragma unroll
    for (int k = 0; k < 8; ++k) {
        unsigned a  = (toks[k] == SEP_ID) ? 1u : 0u;
        unsigned bb = (toks[k] == PAD_ID) ? 1u : 0u;
        A  = a | (A & bb);
        Bf = Bf & bb;
    }

    // Inclusive Kogge-Stone scan of function composition (lower lanes first)
    unsigned incA = A, incB = Bf;
    for (int d = 1; d < 64; d <<= 1) {
        unsigned Al = __shfl_up(incA, d, 64);
        unsigned Bl = __shfl_up(incB, d, 64);
        if (lane >= d) {
            incA = incA | (Al & incB);
            incB = Bl & incB;
        }
    }
    unsigned pin = __shfl_up(incA, 1, 64);
    if (lane == 0) pin = 0u;

    // Recompute the 8 steps with the true incoming state
    unsigned p = pin, skipbits = 0u;
    int cnt = 0;
#pragma unroll
    for (int k = 0; k < 8; ++k) {
        unsigned a  = (toks[k] == SEP_ID) ? 1u : 0u;
        unsigned bb = (toks[k] == PAD_ID) ? 1u : 0u;
        unsigned skip = p & bb;
        skipbits |= skip << k;
        cnt += (int)skip;
        p = a | skip;
    }

    // Exclusive prefix sum of per-lane skip counts -> pad_num at lane start
    int pref = cnt;
    for (int d = 1; d < 64; d <<= 1) {
        int v = __shfl_up(pref, d, 64);
        if (lane >= d) pref += v;
    }
    pref -= cnt;

    int pad = pref;
#pragma unroll
    for (int k = 0; k < 8; ++k) {
        int s = s0 + k;
        unsigned skip = (skipbits >> k) & 1u;
        idx[s * B_SZ + b] = skip ? -1 : (s - pad);
        pad += (int)skip;
    }
}

// Kernel 2: fused gather+add. Identical to R6 except: pe[s_row] is hoisted
// once per wave, and the per-row pe gather sits behind a WAVE-UNIFORM branch
// (pidx is an s_load) taken only when pidx != s_row (<1% of rows). Clean
// iterations issue exactly 2 VMEM ops per 1KB written (tw gather + store).
__global__ void __launch_bounds__(NTHR)
emb_fused_kernel(const int* __restrict__ seq,
                 const float* __restrict__ tw,
                 const float* __restrict__ pe,
                 const int* __restrict__ idx,
                 float* __restrict__ out) {
    const unsigned lane  = threadIdx.x & 63u;
    const unsigned wid_s = (unsigned)__builtin_amdgcn_readfirstlane(threadIdx.x >> 6);
    const unsigned row0  = blockIdx.x * ROWS_PER_BLOCK + wid_s * ROWS_PER_WAVE;
    const unsigned s_row = row0 >> 9;                 // row0 / B_SZ, uniform
    const unsigned doff  = lane * 4u;

    const int* __restrict__ tokp  = seq + row0;   // wave-uniform pointers
    const int* __restrict__ pidxp = idx + row0;
    float* orow = out + (size_t)row0 * D_DIM + doff;

    // Hoisted positional row pe[s_row] — correct for every clean row.
    const f32x4 pv_s = *(const f32x4*)(pe + (size_t)s_row * D_DIM + doff);

#pragma unroll 8
    for (int it = 0; it < ROWS_PER_WAVE; ++it) {
        const int tok  = tokp[it];    // uniform addr -> s_load
        const int pidx = pidxp[it];   // uniform addr -> s_load

        const f32x4 tv = *(const f32x4*)(tw + (size_t)tok * D_DIM + doff);

        f32x4 pv = pv_s;
        if (__builtin_expect(pidx != (int)s_row, 0)) {
            // Rare path: pad-shifted or skipped row. Wave-uniform branch.
            const int   pc = (pidx < 0) ? 0 : pidx;
            const float pm = (pidx < 0) ? 0.0f : 1.0f;
            pv = *(const f32x4*)(pe + (size_t)pc * D_DIM + doff) * pm;
        }

        *(f32x4*)(orow + (size_t)it * D_DIM) = tv + pv;
    }
}

extern "C" void kernel_launch(void* const* d_in, const int* in_sizes, int n_in,
                              void* d_out, int out_size, void* d_ws, size_t ws_size,
                              hipStream_t stream) {
    const int*   seq = (const int*)d_in[0];    // [S, B] int32
    const float* tw  = (const float*)d_in[1];  // [VOCAB, D] f32
    const float* pe  = (const float*)d_in[2];  // [MAX_LEN, D] f32
    float* out = (float*)d_out;                // [S, B, D] f32
    int*   idx = (int*)d_ws;                   // [S, B] int32 scratch (1 MiB)

    // 1) wave-parallel scan: 512 columns, 1 wave each -> 128 blocks x 256
    emb_scan_wave<<<dim3(B_SZ / 4), dim3(256), 0, stream>>>(seq, idx);

    // 2) fused gather+add: 2048 blocks x 256, 128 contiguous rows per block
    emb_fused_kernel<<<dim3(NBLK), dim3(NTHR), 0, stream>>>(seq, tw, pe, idx, out);
}

// Round 9
// 54.696 us; speedup vs baseline: 1.0479x; 1.0360x over previous
//
#include <hip/hip_runtime.h>

// Problem constants (match reference file)
#define S_LEN 512
#define B_SZ  512
#define D_DIM 256
#define SEP_ID 13
#define PAD_ID 1

#define NTHR   256
#define ROWS_PER_WAVE 32
#define ROWS_PER_BLOCK 128                            // 4 waves x 32 rows, all same s
#define NROWS  (S_LEN * B_SZ)                         // 262144
#define NBLK   (NROWS / ROWS_PER_BLOCK)               // 2048 blocks

typedef float f32x4 __attribute__((ext_vector_type(4)));

// Kernel 1: wave-parallel inner-padding state machine (identical to R6).
__global__ void emb_scan_wave(const int* __restrict__ seq,
                              int* __restrict__ idx) {
    const int lane = threadIdx.x & 63;
    const int b = blockIdx.x * (blockDim.x >> 6) + (threadIdx.x >> 6);
    if (b >= B_SZ) return;

    const int s0 = lane * (S_LEN / 64);      // 8 positions per lane
    int toks[8];
#pragma unroll
    for (int k = 0; k < 8; ++k) toks[k] = seq[(s0 + k) * B_SZ + b];

    // Local transfer function over this lane's 8 tokens: f(p) = A | (p & B)
    unsigned A = 0u, Bf = 1u;
#pragma unroll
    for (int k = 0; k < 8; ++k) {
        unsigned a  = (toks[k] == SEP_ID) ? 1u : 0u;
        unsigned bb = (toks[k] == PAD_ID) ? 1u : 0u;
        A  = a | (A & bb);
        Bf = Bf & bb;
    }

    // Inclusive Kogge-Stone scan of function composition (lower lanes first)
    unsigned incA = A, incB = Bf;
    for (int d = 1; d < 64; d <<= 1) {
        unsigned Al = __shfl_up(incA, d, 64);
        unsigned Bl = __shfl_up(incB, d, 64);
        if (lane >= d) {
            incA = incA | (Al & incB);
            incB = Bl & incB;
        }
    }
    unsigned pin = __shfl_up(incA, 1, 64);
    if (lane == 0) pin = 0u;

    // Recompute the 8 steps with the true incoming state
    unsigned p = pin, skipbits = 0u;
    int cnt = 0;
#pragma unroll
    for (int k = 0; k < 8; ++k) {
        unsigned a  = (toks[k] == SEP_ID) ? 1u : 0u;
        unsigned bb = (toks[k] == PAD_ID) ? 1u : 0u;
        unsigned skip = p & bb;
        skipbits |= skip << k;
        cnt += (int)skip;
        p = a | skip;
    }

    // Exclusive prefix sum of per-lane skip counts -> pad_num at lane start
    int pref = cnt;
    for (int d = 1; d < 64; d <<= 1) {
        int v = __shfl_up(pref, d, 64);
        if (lane >= d) pref += v;
    }
    pref -= cnt;

    int pad = pref;
#pragma unroll
    for (int k = 0; k < 8; ++k) {
        int s = s0 + k;
        unsigned skip = (skipbits >> k) & 1u;
        idx[s * B_SZ + b] = skip ? -1 : (s - pad);
        pad += (int)skip;
    }
}

// Kernel 2: fused gather+add — R6's branchless body, but with ALL metadata
// pre-hoisted into local arrays (uniform addrs + constant indices -> batched
// s_loads into SGPRs) and the 32-row loop FULLY unrolled so the scheduler
// can cluster gathers deep ahead of the store/vmcnt chain.
__global__ void __launch_bounds__(NTHR)
emb_fused_kernel(const int* __restrict__ seq,
                 const float* __restrict__ tw,
                 const float* __restrict__ pe,
                 const int* __restrict__ idx,
                 float* __restrict__ out) {
    const unsigned lane  = threadIdx.x & 63u;
    const unsigned wid_s = (unsigned)__builtin_amdgcn_readfirstlane(threadIdx.x >> 6);
    const unsigned row0  = blockIdx.x * ROWS_PER_BLOCK + wid_s * ROWS_PER_WAVE;
    const unsigned doff  = lane * 4u;

    const int* __restrict__ tokp  = seq + row0;   // wave-uniform pointers
    const int* __restrict__ pidxp = idx + row0;
    float* orow = out + (size_t)row0 * D_DIM + doff;

    // Pre-hoist all per-row metadata (constant indices -> SGPR arrays).
    int toks[ROWS_PER_WAVE], pidxs[ROWS_PER_WAVE];
#pragma unroll
    for (int it = 0; it < ROWS_PER_WAVE; ++it) {
        toks[it]  = tokp[it];
        pidxs[it] = pidxp[it];
    }

#pragma unroll
    for (int it = 0; it < ROWS_PER_WAVE; ++it) {
        const int tok  = toks[it];
        const int pidx = pidxs[it];

        const f32x4 tv = *(const f32x4*)(tw + (size_t)tok * D_DIM + doff);
        const int   pc = (pidx < 0) ? 0 : pidx;
        const f32x4 pv = *(const f32x4*)(pe + (size_t)pc * D_DIM + doff);
        const float pm = (pidx < 0) ? 0.0f : 1.0f;

        f32x4 o = tv + pv * pm;
        *(f32x4*)(orow + (size_t)it * D_DIM) = o;
    }
}

extern "C" void kernel_launch(void* const* d_in, const int* in_sizes, int n_in,
                              void* d_out, int out_size, void* d_ws, size_t ws_size,
                              hipStream_t stream) {
    const int*   seq = (const int*)d_in[0];    // [S, B] int32
    const float* tw  = (const float*)d_in[1];  // [VOCAB, D] f32
    const float* pe  = (const float*)d_in[2];  // [MAX_LEN, D] f32
    float* out = (float*)d_out;                // [S, B, D] f32
    int*   idx = (int*)d_ws;                   // [S, B] int32 scratch (1 MiB)

    // 1) wave-parallel scan: 512 columns, 1 wave each -> 128 blocks x 256
    emb_scan_wave<<<dim3(B_SZ / 4), dim3(256), 0, stream>>>(seq, idx);

    // 2) fused gather+add: 2048 blocks x 256, 128 contiguous rows per block
    emb_fused_kernel<<<dim3(NBLK), dim3(NTHR), 0, stream>>>(seq, tw, pe, idx, out);
}